// Round 2
// baseline (256.100 us; speedup 1.0000x reference)
//
#include <hip/hip_runtime.h>

#define NTOT 100000

typedef float f32x4 __attribute__((ext_vector_type(4)));
typedef short s16x8 __attribute__((ext_vector_type(8)));
typedef unsigned short u16;
typedef unsigned int u32;

__device__ __forceinline__ u16 bfbits(float f) {
    return __builtin_bit_cast(u16, (__bf16)f);
}
__device__ __forceinline__ u32 packbf2(float a, float b) {
    return (u32)bfbits(a) | ((u32)bfbits(b) << 16);
}
__device__ __forceinline__ float bf2f(u16 u) {
    u32 v = ((u32)u) << 16;
    return __builtin_bit_cast(float, v);
}
__device__ __forceinline__ s16x8 cvt8(const float* __restrict__ p) {
    f32x4 lo = *(const f32x4*)p;
    f32x4 hi = *(const f32x4*)(p + 4);
    s16x8 r;
#pragma unroll
    for (int e = 0; e < 4; ++e) r[e] = (short)bfbits(lo[e]);
#pragma unroll
    for (int e = 0; e < 4; ++e) r[4 + e] = (short)bfbits(hi[e]);
    return r;
}

// ---------------- kernel 1: Cayley weights -------------------------------
__global__ void k_weights(const float* __restrict__ ev, const float* __restrict__ hp,
                          const float* __restrict__ ap, float* __restrict__ br,
                          float* __restrict__ bi) {
    int k = threadIdx.x;
    float h = hp[0], alpha = ap[0];
    float t = h * (ev[k] - alpha);
    float inv = 1.0f / (t * t + 1.0f);
    float b_re = (t * t - 1.0f) * inv;
    float b_im = -2.0f * t * inv;
    float cr = b_re, ci = b_im;
    br[k] = cr; bi[k] = ci;
#pragma unroll
    for (int j = 1; j < 8; ++j) {
        float nr = cr * b_re - ci * b_im;
        float ni = cr * b_im + ci * b_re;
        cr = nr; ci = ni;
        br[j * 256 + k] = cr;
        bi[j * 256 + k] = ci;
    }
}

// ---------------- kernel 2: P_partial(bf16) = E^T @ x over an N-chunk ----
// grid = 2*chunks; block 512 (8 waves). Block tile: 128(k) x 256(i) x 64(n).
// LDS layout: row r (k or i), 64 n as 32 pairs; pair pr stored at
//   byte = r*128 + (((pr>>2) ^ (r&7))*16) + (pr&3)*4
// -> ds_read_b128 conflict-free, ds_write_b32 2-way (free).
__global__ __launch_bounds__(512, 4) void k_gemm1(
    const float* __restrict__ E, const float* __restrict__ X,
    u16* __restrict__ Pp, int NB) {
    int bx = blockIdx.x;
    int k0 = (bx & 1) * 128;
    int chunk = bx >> 1;
    int nStart = chunk * NB;
    int nEnd = min(nStart + NB, NTOT);

    __shared__ alignas(16) u16 Et[128 * 64];   // 16 KB
    __shared__ alignas(16) u16 Xt[256 * 64];   // 32 KB

    int t = threadIdx.x;
    int lane = t & 63;
    int w = t >> 6;
    int wk = w & 1;        // k-half (64)
    int wi = w >> 1;       // i-quarter (64)
    int l15 = lane & 15, lhi = lane >> 4;
    int np = t & 15;       // n-pair within window
    int kq = t >> 4;       // k-quad 0..31

    f32x4 acc[4][4] = {};

    for (int n0 = nStart; n0 < nEnd; n0 += 64) {
        // ---- stage E tile [n0..n0+63][k0..k0+127], 2 passes ----
#pragma unroll
        for (int h = 0; h < 2; ++h) {
            int n = n0 + h * 32 + np * 2;
            int na = (n < nEnd) ? n : nStart;
            int nb = (n + 1 < nEnd) ? (n + 1) : nStart;
            f32x4 r0 = *(const f32x4*)(E + (size_t)na * 256 + k0 + kq * 4);
            f32x4 r1 = *(const f32x4*)(E + (size_t)nb * 256 + k0 + kq * 4);
            float m0 = (n < nEnd) ? 1.0f : 0.0f;
            float m1 = (n + 1 < nEnd) ? 1.0f : 0.0f;
            r0 *= m0; r1 *= m1;
            int pr = h * 16 + np;
#pragma unroll
            for (int e = 0; e < 4; ++e) {
                int row = kq * 4 + e;
                int slot = (pr >> 2) ^ (row & 7);
                *(u32*)((char*)Et + row * 128 + slot * 16 + (pr & 3) * 4) =
                    packbf2(r0[e], r1[e]);
            }
        }
        // ---- stage X tile [n0..n0+63][0..255], 4 passes ----
#pragma unroll
        for (int hs = 0; hs < 4; ++hs) {
            int h = hs >> 1, s = hs & 1;
            int kqx = kq + s * 32;
            int n = n0 + h * 32 + np * 2;
            int na = (n < nEnd) ? n : nStart;
            int nb = (n + 1 < nEnd) ? (n + 1) : nStart;
            f32x4 r0 = *(const f32x4*)(X + (size_t)na * 256 + kqx * 4);
            f32x4 r1 = *(const f32x4*)(X + (size_t)nb * 256 + kqx * 4);
            float m0 = (n < nEnd) ? 1.0f : 0.0f;
            float m1 = (n + 1 < nEnd) ? 1.0f : 0.0f;
            r0 *= m0; r1 *= m1;
            int pr = h * 16 + np;
#pragma unroll
            for (int e = 0; e < 4; ++e) {
                int row = kqx * 4 + e;
                int slot = (pr >> 2) ^ (row & 7);
                *(u32*)((char*)Xt + row * 128 + slot * 16 + (pr & 3) * 4) =
                    packbf2(r0[e], r1[e]);
            }
        }
        __syncthreads();

#pragma unroll
        for (int ks = 0; ks < 2; ++ks) {
            s16x8 a[4], b[4];
#pragma unroll
            for (int m = 0; m < 4; ++m) {
                int row = wk * 64 + m * 16 + l15;
                int slot = (ks * 4 + lhi) ^ (row & 7);
                a[m] = *(const s16x8*)((char*)Et + row * 128 + slot * 16);
            }
#pragma unroll
            for (int c = 0; c < 4; ++c) {
                int row = wi * 64 + c * 16 + l15;
                int slot = (ks * 4 + lhi) ^ (row & 7);
                b[c] = *(const s16x8*)((char*)Xt + row * 128 + slot * 16);
            }
#pragma unroll
            for (int m = 0; m < 4; ++m)
#pragma unroll
                for (int c = 0; c < 4; ++c)
                    acc[m][c] = __builtin_amdgcn_mfma_f32_16x16x32_bf16(
                        a[m], b[c], acc[m][c], 0, 0, 0);
        }
        __syncthreads();
    }

    u16* dst = Pp + (size_t)chunk * 65536;
#pragma unroll
    for (int m = 0; m < 4; ++m) {
#pragma unroll
        for (int c = 0; c < 4; ++c) {
            int ii = wi * 64 + c * 16 + l15;
#pragma unroll
            for (int r = 0; r < 4; ++r) {
                int kk = k0 + wk * 64 + m * 16 + lhi * 4 + r;
                dst[kk * 256 + ii] = bfbits(acc[m][c][r]);
            }
        }
    }
}

// ---------------- kernel 3: reduce bf16 partials -> Pb (bf16) ------------
__global__ void k_reduceP(const u16* __restrict__ Pp,
                          u16* __restrict__ Pb, int chunks) {
    int g = blockIdx.x * 256 + threadIdx.x;   // 0..65535
    float s = 0.f;
    for (int c = 0; c < chunks; ++c) s += bf2f(Pp[(size_t)c * 65536 + g]);
    Pb[g] = bfbits(s);
}

// ---------------- kernel 4: T[c] = P @ W_c^T (17 small GEMMs) ------------
// grid = 17*8 (c, k-tile of 32); block 256 (4 waves = 4 o-quarters).
__global__ __launch_bounds__(256, 4) void k_smallgemm(
    const u16* __restrict__ Pb, const float* __restrict__ c0,
    const float* __restrict__ cjr, const float* __restrict__ cji,
    float* __restrict__ T) {
    int c = blockIdx.x >> 3;
    int k0 = (blockIdx.x & 7) * 32;
    const float* W = (c == 0) ? c0 : (c <= 8 ? (cjr + (size_t)(c - 1) * 65536)
                                             : (cji + (size_t)(c - 9) * 65536));
    int t = threadIdx.x, lane = t & 63, wi = t >> 6;
    int l15 = lane & 15, lhi = lane >> 4;
    f32x4 acc[2][4] = {};
    for (int is = 0; is < 256; is += 32) {
        s16x8 a[2], b[4];
#pragma unroll
        for (int m = 0; m < 2; ++m)
            a[m] = *(const s16x8*)(Pb + (k0 + m * 16 + l15) * 256 + is + lhi * 8);
#pragma unroll
        for (int cf = 0; cf < 4; ++cf)
            b[cf] = cvt8(W + (size_t)(wi * 64 + cf * 16 + l15) * 256 + is + lhi * 8);
#pragma unroll
        for (int m = 0; m < 2; ++m)
#pragma unroll
            for (int cf = 0; cf < 4; ++cf)
                acc[m][cf] = __builtin_amdgcn_mfma_f32_16x16x32_bf16(
                    a[m], b[cf], acc[m][cf], 0, 0, 0);
    }
    float* dst = T + (size_t)c * 65536;
#pragma unroll
    for (int m = 0; m < 2; ++m) {
#pragma unroll
        for (int cf = 0; cf < 4; ++cf) {
            int oo = wi * 64 + cf * 16 + l15;
#pragma unroll
            for (int r = 0; r < 4; ++r) {
                int kk = k0 + m * 16 + lhi * 4 + r;
                dst[kk * 256 + oo] = acc[m][cf][r];
            }
        }
    }
}

// ---------------- kernel 5: combine T -> Qt bf16 (transposed) ------------
// Q[k,o] = T0 + 2*sum_j (br[j,k]*Tr[j] - bi[j,k]*Ti[j]); Qt[o][k] = bf16(Q)
__global__ void k_combine(const float* __restrict__ T, const float* __restrict__ br,
                          const float* __restrict__ bi, u16* __restrict__ Qt) {
    int t = threadIdx.x;
    int k = blockIdx.x * 4 + (t >> 6);
    int o4 = (t & 63) * 4;
    f32x4 q = *(const f32x4*)(T + (size_t)k * 256 + o4);
#pragma unroll
    for (int j = 0; j < 8; ++j) {
        float brv = br[j * 256 + k], biv = bi[j * 256 + k];
        f32x4 tr = *(const f32x4*)(T + (size_t)(1 + j) * 65536 + k * 256 + o4);
        f32x4 ti = *(const f32x4*)(T + (size_t)(9 + j) * 65536 + k * 256 + o4);
        q += 2.0f * (brv * tr - biv * ti);
    }
#pragma unroll
    for (int e = 0; e < 4; ++e) Qt[(size_t)(o4 + e) * 256 + k] = bfbits(q[e]);
}

// ---------------- kernel 6: out = E @ Q ----------------------------------
// grid = ceil(N/64); block 256 (4 waves = o-quarters). Reg-double-buffered;
// A = Qt rows (o as M-dim) so acc regs = 4 consecutive o -> dwordx4 stores.
__global__ __launch_bounds__(256, 2) void k_gemm2(
    const float* __restrict__ E, const u16* __restrict__ Qt,
    float* __restrict__ out) {
    int n0 = blockIdx.x * 64;
    int t = threadIdx.x, lane = t & 63, wo = t >> 6;
    int l15 = lane & 15, lhi = lane >> 4;
    int o0 = wo * 64;

    int nidx[4];
#pragma unroll
    for (int cn = 0; cn < 4; ++cn) {
        int n = n0 + cn * 16 + l15;
        nidx[cn] = (n < NTOT) ? n : (NTOT - 1);
    }
    const u16* qbase = Qt + (size_t)(o0 + l15) * 256 + lhi * 8;

    f32x4 acc[4][4] = {};
    f32x4 er0[4][2], er1[4][2];
    s16x8 aq0[4], aq1[4];

#define LOADE(ER, KS)                                                      \
    _Pragma("unroll") for (int cn = 0; cn < 4; ++cn) {                     \
        const float* p = E + (size_t)nidx[cn] * 256 + (KS) + lhi * 8;      \
        ER[cn][0] = *(const f32x4*)p;                                      \
        ER[cn][1] = *(const f32x4*)(p + 4);                                \
    }
#define LOADQ(AQ, KS)                                                      \
    _Pragma("unroll") for (int mo = 0; mo < 4; ++mo)                       \
        AQ[mo] = *(const s16x8*)(qbase + mo * 4096 + (KS));
#define COMPUTE(ER, AQ)                                                    \
    {                                                                      \
        s16x8 bfr[4];                                                      \
        _Pragma("unroll") for (int cn = 0; cn < 4; ++cn) {                 \
            _Pragma("unroll") for (int e = 0; e < 4; ++e) {                \
                bfr[cn][e] = (short)bfbits(ER[cn][0][e]);                  \
                bfr[cn][4 + e] = (short)bfbits(ER[cn][1][e]);              \
            }                                                              \
        }                                                                  \
        _Pragma("unroll") for (int mo = 0; mo < 4; ++mo)                   \
            _Pragma("unroll") for (int cn = 0; cn < 4; ++cn)               \
                acc[mo][cn] = __builtin_amdgcn_mfma_f32_16x16x32_bf16(     \
                    AQ[mo], bfr[cn], acc[mo][cn], 0, 0, 0);                \
    }

    LOADE(er0, 0);   LOADQ(aq0, 0);
    LOADE(er1, 32);  LOADQ(aq1, 32);  COMPUTE(er0, aq0);
    LOADE(er0, 64);  LOADQ(aq0, 64);  COMPUTE(er1, aq1);
    LOADE(er1, 96);  LOADQ(aq1, 96);  COMPUTE(er0, aq0);
    LOADE(er0, 128); LOADQ(aq0, 128); COMPUTE(er1, aq1);
    LOADE(er1, 160); LOADQ(aq1, 160); COMPUTE(er0, aq0);
    LOADE(er0, 192); LOADQ(aq0, 192); COMPUTE(er1, aq1);
    LOADE(er1, 224); LOADQ(aq1, 224); COMPUTE(er0, aq0);
    COMPUTE(er1, aq1);
#undef LOADE
#undef LOADQ
#undef COMPUTE

#pragma unroll
    for (int mo = 0; mo < 4; ++mo) {
#pragma unroll
        for (int cn = 0; cn < 4; ++cn) {
            int n = n0 + cn * 16 + l15;
            if (n < NTOT)
                *(f32x4*)(out + (size_t)n * 256 + o0 + mo * 16 + lhi * 4) =
                    acc[mo][cn];
        }
    }
}

// ---------------- host ---------------------------------------------------
extern "C" void kernel_launch(void* const* d_in, const int* in_sizes, int n_in,
                              void* d_out, int out_size, void* d_ws, size_t ws_size,
                              hipStream_t stream) {
    const float* x   = (const float*)d_in[0];
    const float* ev  = (const float*)d_in[1];
    const float* E   = (const float*)d_in[2];
    const float* hp  = (const float*)d_in[3];
    const float* ap  = (const float*)d_in[4];
    const float* c0  = (const float*)d_in[5];
    const float* cjr = (const float*)d_in[6];
    const float* cji = (const float*)d_in[7];
    float* out = (float*)d_out;

    char* ws = (char*)d_ws;
    float* br = (float*)(ws + 0);                 // 8 KB
    float* bi = (float*)(ws + 8192);              // 8 KB
    u16*   Pb = (u16*)(ws + 16384);               // 128 KB
    u16*   Qt = (u16*)(ws + 147456);              // 128 KB
    float* T  = (float*)(ws + 278528);            // 17*256 KB
    const size_t pp_off = 4734976;
    u16*   Pp = (u16*)(ws + pp_off);              // chunks * 128 KB (bf16)

    size_t avail = (ws_size > pp_off) ? (ws_size - pp_off) : 0;
    int chunks = (int)(avail / 131072);
    if (chunks > 256) chunks = 256;
    if (chunks < 1) chunks = 1;
    int NB = (NTOT + chunks - 1) / chunks;

    k_weights<<<1, 256, 0, stream>>>(ev, hp, ap, br, bi);
    k_gemm1<<<2 * chunks, 512, 0, stream>>>(E, x, Pp, NB);
    k_reduceP<<<256, 256, 0, stream>>>(Pp, Pb, chunks);
    k_smallgemm<<<17 * 8, 256, 0, stream>>>(Pb, c0, cjr, cji, T);
    k_combine<<<64, 256, 0, stream>>>(T, br, bi, Qt);
    k_gemm2<<<(NTOT + 63) / 64, 256, 0, stream>>>(E, Qt, out);
}

// Round 3
// 231.894 us; speedup vs baseline: 1.1044x; 1.1044x over previous
//
#include <hip/hip_runtime.h>

#define NTOT 100000

typedef float f32x4 __attribute__((ext_vector_type(4)));
typedef short s16x8 __attribute__((ext_vector_type(8)));
typedef short s16x4 __attribute__((ext_vector_type(4)));
typedef unsigned short u16;
typedef unsigned int u32;

__device__ __forceinline__ u16 bfbits(float f) {
    return __builtin_bit_cast(u16, (__bf16)f);
}
__device__ __forceinline__ u32 packbf2(float a, float b) {
    return (u32)bfbits(a) | ((u32)bfbits(b) << 16);
}
__device__ __forceinline__ float bf2f(u16 u) {
    u32 v = ((u32)u) << 16;
    return __builtin_bit_cast(float, v);
}
__device__ __forceinline__ s16x8 cvt8(const float* __restrict__ p) {
    f32x4 lo = *(const f32x4*)p;
    f32x4 hi = *(const f32x4*)(p + 4);
    s16x8 r;
#pragma unroll
    for (int e = 0; e < 4; ++e) r[e] = (short)bfbits(lo[e]);
#pragma unroll
    for (int e = 0; e < 4; ++e) r[4 + e] = (short)bfbits(hi[e]);
    return r;
}

// ---------------- kernel 1: Cayley weights -------------------------------
__global__ void k_weights(const float* __restrict__ ev, const float* __restrict__ hp,
                          const float* __restrict__ ap, float* __restrict__ br,
                          float* __restrict__ bi) {
    int k = threadIdx.x;
    float h = hp[0], alpha = ap[0];
    float t = h * (ev[k] - alpha);
    float inv = 1.0f / (t * t + 1.0f);
    float b_re = (t * t - 1.0f) * inv;
    float b_im = -2.0f * t * inv;
    float cr = b_re, ci = b_im;
    br[k] = cr; bi[k] = ci;
#pragma unroll
    for (int j = 1; j < 8; ++j) {
        float nr = cr * b_re - ci * b_im;
        float ni = cr * b_im + ci * b_re;
        cr = nr; ci = ni;
        br[j * 256 + k] = cr;
        bi[j * 256 + k] = ci;
    }
}

// ---------------- kernel 2: P_partial(bf16) = E^T @ x --------------------
// grid = 4*chunks (2 k-tiles x 2 i-tiles); block 512 (8 waves).
// Tile 128k x 128i x 64n window. Wave = 32k x 64i -> acc[2][4] = 32 regs.
// T14 async split: write LDS(w) -> issue loads(w+1) -> barrier -> MFMA(w).
__global__ __launch_bounds__(512, 4) void k_gemm1(
    const float* __restrict__ E, const float* __restrict__ X,
    u16* __restrict__ Pp, int NB) {
    int bx = blockIdx.x;
    int tk = bx & 1, ti = (bx >> 1) & 1, chunk = bx >> 2;
    int k0 = tk * 128, i0 = ti * 128;
    int nStart = chunk * NB;
    int nEnd = min(nStart + NB, NTOT);
    if (nEnd < nStart) nEnd = nStart;

    __shared__ alignas(16) u16 Et[128 * 64];   // 16 KB, slot-XOR layout
    __shared__ alignas(16) u16 Xt[128 * 64];   // 16 KB

    int t = threadIdx.x, lane = t & 63, w = t >> 6;
    int wk = w & 3, wi = w >> 2;          // k-quarter(32), i-half(64)
    int l15 = lane & 15, lhi = lane >> 4;
    int np = t & 15, cq = t >> 4;         // staging: n-pair, col-quad

    const float* Ebase = E + (size_t)(np * 2) * 256 + k0 + cq * 4;
    const float* Xbase = X + (size_t)(np * 2) * 256 + i0 + cq * 4;

    f32x4 v[8];
    f32x4 acc[2][4] = {};

    int nwin = (nEnd - nStart) >> 6;
    int ntail = (nEnd - nStart) & 63;
    int n0 = nStart;

#define LOADW(N0)                                                           \
    {                                                                       \
        size_t roff = (size_t)(N0) * 256;                                   \
        _Pragma("unroll") for (int h = 0; h < 2; ++h) {                     \
            v[h * 2 + 0] = *(const f32x4*)(Ebase + roff + (size_t)(h * 32) * 256);       \
            v[h * 2 + 1] = *(const f32x4*)(Ebase + roff + (size_t)(h * 32 + 1) * 256);   \
            v[4 + h * 2 + 0] = *(const f32x4*)(Xbase + roff + (size_t)(h * 32) * 256);   \
            v[4 + h * 2 + 1] = *(const f32x4*)(Xbase + roff + (size_t)(h * 32 + 1) * 256);\
        }                                                                   \
    }

#define WRITEW()                                                            \
    _Pragma("unroll") for (int h = 0; h < 2; ++h) {                         \
        int pr = h * 16 + np;                                               \
        _Pragma("unroll") for (int e = 0; e < 4; ++e) {                     \
            int c = cq * 4 + e;                                             \
            int byte = c * 128 + (((pr >> 2) ^ (c & 7)) * 16) + (pr & 3) * 4; \
            *(u32*)((char*)Et + byte) = packbf2(v[h * 2][e], v[h * 2 + 1][e]); \
            *(u32*)((char*)Xt + byte) = packbf2(v[4 + h * 2][e], v[4 + h * 2 + 1][e]); \
        }                                                                   \
    }

#define COMPUTEW()                                                          \
    _Pragma("unroll") for (int ks = 0; ks < 2; ++ks) {                      \
        s16x8 a[2], b[4];                                                   \
        _Pragma("unroll") for (int m = 0; m < 2; ++m) {                     \
            int row = wk * 32 + m * 16 + l15;                               \
            int slot = (ks * 4 + lhi) ^ (row & 7);                          \
            a[m] = *(const s16x8*)((char*)Et + row * 128 + slot * 16);      \
        }                                                                   \
        _Pragma("unroll") for (int c = 0; c < 4; ++c) {                     \
            int row = wi * 64 + c * 16 + l15;                               \
            int slot = (ks * 4 + lhi) ^ (row & 7);                          \
            b[c] = *(const s16x8*)((char*)Xt + row * 128 + slot * 16);      \
        }                                                                   \
        _Pragma("unroll") for (int m = 0; m < 2; ++m)                       \
            _Pragma("unroll") for (int c = 0; c < 4; ++c)                   \
                acc[m][c] = __builtin_amdgcn_mfma_f32_16x16x32_bf16(        \
                    a[m], b[c], acc[m][c], 0, 0, 0);                        \
    }

    if (nwin) LOADW(n0);
    for (int i = 0; i < nwin; ++i) {
        __syncthreads();
        WRITEW();
        if (i + 1 < nwin) LOADW(n0 + 64);
        __syncthreads();
        COMPUTEW();
        n0 += 64;
    }
    if (ntail) {
        __syncthreads();
#pragma unroll
        for (int h = 0; h < 2; ++h) {
            int na = n0 + h * 32 + np * 2;
            int nb = na + 1;
            int ca = (na < nEnd) ? na : nStart;
            int cb = (nb < nEnd) ? nb : nStart;
            float ma = (na < nEnd) ? 1.0f : 0.0f;
            float mb = (nb < nEnd) ? 1.0f : 0.0f;
            v[h * 2 + 0] = *(const f32x4*)(E + (size_t)ca * 256 + k0 + cq * 4) * ma;
            v[h * 2 + 1] = *(const f32x4*)(E + (size_t)cb * 256 + k0 + cq * 4) * mb;
            v[4 + h * 2 + 0] = *(const f32x4*)(X + (size_t)ca * 256 + i0 + cq * 4) * ma;
            v[4 + h * 2 + 1] = *(const f32x4*)(X + (size_t)cb * 256 + i0 + cq * 4) * mb;
        }
        WRITEW();
        __syncthreads();
        COMPUTEW();
    }
#undef LOADW
#undef WRITEW
#undef COMPUTEW

    u16* dst = Pp + (size_t)chunk * 65536;
#pragma unroll
    for (int m = 0; m < 2; ++m) {
#pragma unroll
        for (int cf = 0; cf < 4; ++cf) {
            int ii = i0 + wi * 64 + cf * 16 + l15;
#pragma unroll
            for (int r = 0; r < 4; ++r) {
                int kk = k0 + wk * 32 + m * 16 + lhi * 4 + r;
                dst[kk * 256 + ii] = bfbits(acc[m][cf][r]);
            }
        }
    }
}

// ---------------- kernel 3: reduce bf16 partials -> Pb (bf16) ------------
// grid 64 x 256; thread owns a g-quad; coalesced 8B loads per chunk.
__global__ void k_reduceP(const u16* __restrict__ Pp,
                          u16* __restrict__ Pb, int chunks) {
    int g4 = (blockIdx.x * 256 + threadIdx.x) * 4;
    float s0 = 0.f, s1 = 0.f, s2 = 0.f, s3 = 0.f;
    for (int c = 0; c < chunks; ++c) {
        s16x4 vv = *(const s16x4*)(Pp + (size_t)c * 65536 + g4);
        s0 += bf2f((u16)vv[0]); s1 += bf2f((u16)vv[1]);
        s2 += bf2f((u16)vv[2]); s3 += bf2f((u16)vv[3]);
    }
    s16x4 o;
    o[0] = (short)bfbits(s0); o[1] = (short)bfbits(s1);
    o[2] = (short)bfbits(s2); o[3] = (short)bfbits(s3);
    *(s16x4*)(Pb + g4) = o;
}

// ---------------- kernel 4: T[c] = P @ W_c^T (17 small GEMMs) ------------
__global__ __launch_bounds__(256, 4) void k_smallgemm(
    const u16* __restrict__ Pb, const float* __restrict__ c0,
    const float* __restrict__ cjr, const float* __restrict__ cji,
    float* __restrict__ T) {
    int c = blockIdx.x >> 3;
    int k0 = (blockIdx.x & 7) * 32;
    const float* W = (c == 0) ? c0 : (c <= 8 ? (cjr + (size_t)(c - 1) * 65536)
                                             : (cji + (size_t)(c - 9) * 65536));
    int t = threadIdx.x, lane = t & 63, wi = t >> 6;
    int l15 = lane & 15, lhi = lane >> 4;
    f32x4 acc[2][4] = {};
    for (int is = 0; is < 256; is += 32) {
        s16x8 a[2], b[4];
#pragma unroll
        for (int m = 0; m < 2; ++m)
            a[m] = *(const s16x8*)(Pb + (k0 + m * 16 + l15) * 256 + is + lhi * 8);
#pragma unroll
        for (int cf = 0; cf < 4; ++cf)
            b[cf] = cvt8(W + (size_t)(wi * 64 + cf * 16 + l15) * 256 + is + lhi * 8);
#pragma unroll
        for (int m = 0; m < 2; ++m)
#pragma unroll
            for (int cf = 0; cf < 4; ++cf)
                acc[m][cf] = __builtin_amdgcn_mfma_f32_16x16x32_bf16(
                    a[m], b[cf], acc[m][cf], 0, 0, 0);
    }
    float* dst = T + (size_t)c * 65536;
#pragma unroll
    for (int m = 0; m < 2; ++m) {
#pragma unroll
        for (int cf = 0; cf < 4; ++cf) {
            int oo = wi * 64 + cf * 16 + l15;
#pragma unroll
            for (int r = 0; r < 4; ++r) {
                int kk = k0 + m * 16 + lhi * 4 + r;
                dst[kk * 256 + oo] = acc[m][cf][r];
            }
        }
    }
}

// ---------------- kernel 5: combine T -> Qt bf16 (transposed) ------------
__global__ void k_combine(const float* __restrict__ T, const float* __restrict__ br,
                          const float* __restrict__ bi, u16* __restrict__ Qt) {
    int t = threadIdx.x;
    int k = blockIdx.x * 4 + (t >> 6);
    int o4 = (t & 63) * 4;
    f32x4 q = *(const f32x4*)(T + (size_t)k * 256 + o4);
#pragma unroll
    for (int j = 0; j < 8; ++j) {
        float brv = br[j * 256 + k], biv = bi[j * 256 + k];
        f32x4 tr = *(const f32x4*)(T + (size_t)(1 + j) * 65536 + k * 256 + o4);
        f32x4 ti = *(const f32x4*)(T + (size_t)(9 + j) * 65536 + k * 256 + o4);
        q += 2.0f * (brv * tr - biv * ti);
    }
#pragma unroll
    for (int e = 0; e < 4; ++e) Qt[(size_t)(o4 + e) * 256 + k] = bfbits(q[e]);
}

// ---------------- kernel 6: out = E @ Q ----------------------------------
// grid = 3125 (exact: 3125*32 = 100000); block 256 = 4 waves (o-quarters).
// Per wave: 32n x 64o, acc[4][2] = 32 regs; 2-deep reg pipeline.
__global__ __launch_bounds__(256, 4) void k_gemm2(
    const float* __restrict__ E, const u16* __restrict__ Qt,
    float* __restrict__ out) {
    int n0 = blockIdx.x * 32;
    int t = threadIdx.x, lane = t & 63, wo = t >> 6;
    int l15 = lane & 15, lhi = lane >> 4;
    int o0 = wo * 64;
    const u16* qbase = Qt + (size_t)(o0 + l15) * 256 + lhi * 8;
    const float* e0 = E + (size_t)(n0 + l15) * 256 + lhi * 8;
    const float* e1 = e0 + 16 * 256;

    f32x4 acc[4][2] = {};
    s16x8 aqA[4], aqB[4];
    f32x4 erA[4], erB[4];

#define LQ(AQ, KS)                                                          \
    _Pragma("unroll") for (int mo = 0; mo < 4; ++mo)                        \
        AQ[mo] = *(const s16x8*)(qbase + mo * 4096 + (KS));
#define LE(ER, KS)                                                          \
    {                                                                       \
        ER[0] = *(const f32x4*)(e0 + (KS));                                 \
        ER[1] = *(const f32x4*)(e0 + (KS) + 4);                             \
        ER[2] = *(const f32x4*)(e1 + (KS));                                 \
        ER[3] = *(const f32x4*)(e1 + (KS) + 4);                             \
    }
#define CMP(AQ, ER)                                                         \
    {                                                                       \
        s16x8 bfr[2];                                                       \
        _Pragma("unroll") for (int e = 0; e < 4; ++e) {                     \
            bfr[0][e] = (short)bfbits(ER[0][e]);                            \
            bfr[0][4 + e] = (short)bfbits(ER[1][e]);                        \
            bfr[1][e] = (short)bfbits(ER[2][e]);                            \
            bfr[1][4 + e] = (short)bfbits(ER[3][e]);                        \
        }                                                                   \
        _Pragma("unroll") for (int mo = 0; mo < 4; ++mo) {                  \
            acc[mo][0] = __builtin_amdgcn_mfma_f32_16x16x32_bf16(           \
                AQ[mo], bfr[0], acc[mo][0], 0, 0, 0);                       \
            acc[mo][1] = __builtin_amdgcn_mfma_f32_16x16x32_bf16(           \
                AQ[mo], bfr[1], acc[mo][1], 0, 0, 0);                       \
        }                                                                   \
    }

    LQ(aqA, 0);   LE(erA, 0);
    LQ(aqB, 32);  LE(erB, 32);  CMP(aqA, erA);
    LQ(aqA, 64);  LE(erA, 64);  CMP(aqB, erB);
    LQ(aqB, 96);  LE(erB, 96);  CMP(aqA, erA);
    LQ(aqA, 128); LE(erA, 128); CMP(aqB, erB);
    LQ(aqB, 160); LE(erB, 160); CMP(aqA, erA);
    LQ(aqA, 192); LE(erA, 192); CMP(aqB, erB);
    LQ(aqB, 224); LE(erB, 224); CMP(aqA, erA);
    CMP(aqB, erB);
#undef LQ
#undef LE
#undef CMP

#pragma unroll
    for (int mo = 0; mo < 4; ++mo) {
#pragma unroll
        for (int cn = 0; cn < 2; ++cn) {
            int n = n0 + cn * 16 + l15;
            *(f32x4*)(out + (size_t)n * 256 + o0 + mo * 16 + lhi * 4) = acc[mo][cn];
        }
    }
}

// ---------------- host ---------------------------------------------------
extern "C" void kernel_launch(void* const* d_in, const int* in_sizes, int n_in,
                              void* d_out, int out_size, void* d_ws, size_t ws_size,
                              hipStream_t stream) {
    const float* x   = (const float*)d_in[0];
    const float* ev  = (const float*)d_in[1];
    const float* E   = (const float*)d_in[2];
    const float* hp  = (const float*)d_in[3];
    const float* ap  = (const float*)d_in[4];
    const float* c0  = (const float*)d_in[5];
    const float* cjr = (const float*)d_in[6];
    const float* cji = (const float*)d_in[7];
    float* out = (float*)d_out;

    char* ws = (char*)d_ws;
    float* br = (float*)(ws + 0);                 // 8 KB
    float* bi = (float*)(ws + 8192);              // 8 KB
    u16*   Pb = (u16*)(ws + 16384);               // 128 KB
    u16*   Qt = (u16*)(ws + 147456);              // 128 KB
    float* T  = (float*)(ws + 278528);            // 17*256 KB
    const size_t pp_off = 4734976;
    u16*   Pp = (u16*)(ws + pp_off);              // chunks * 128 KB (bf16)

    size_t avail = (ws_size > pp_off) ? (ws_size - pp_off) : 0;
    int chunks = (int)(avail / 131072);
    if (chunks > 128) chunks = 128;
    if (chunks < 1) chunks = 1;
    int NB = (NTOT + chunks - 1) / chunks;

    k_weights<<<1, 256, 0, stream>>>(ev, hp, ap, br, bi);
    k_gemm1<<<4 * chunks, 512, 0, stream>>>(E, x, Pp, NB);
    k_reduceP<<<64, 256, 0, stream>>>(Pp, Pb, chunks);
    k_smallgemm<<<17 * 8, 256, 0, stream>>>(Pb, c0, cjr, cji, T);
    k_combine<<<64, 256, 0, stream>>>(T, br, bi, Qt);
    k_gemm2<<<3125, 256, 0, stream>>>(E, Qt, out);
}

// Round 4
// 216.334 us; speedup vs baseline: 1.1838x; 1.0719x over previous
//
#include <hip/hip_runtime.h>

#define NTOT 100000

typedef float f32x4 __attribute__((ext_vector_type(4)));
typedef short s16x8 __attribute__((ext_vector_type(8)));
typedef short s16x4 __attribute__((ext_vector_type(4)));
typedef unsigned short u16;
typedef unsigned int u32;

__device__ __forceinline__ u16 bfbits(float f) {
    return __builtin_bit_cast(u16, (__bf16)f);
}
__device__ __forceinline__ u32 packbf2(float a, float b) {
    return (u32)bfbits(a) | ((u32)bfbits(b) << 16);
}
__device__ __forceinline__ float bf2f(u16 u) {
    u32 v = ((u32)u) << 16;
    return __builtin_bit_cast(float, v);
}
__device__ __forceinline__ s16x8 cvt8(const float* __restrict__ p) {
    f32x4 lo = *(const f32x4*)p;
    f32x4 hi = *(const f32x4*)(p + 4);
    s16x8 r;
#pragma unroll
    for (int e = 0; e < 4; ++e) r[e] = (short)bfbits(lo[e]);
#pragma unroll
    for (int e = 0; e < 4; ++e) r[4 + e] = (short)bfbits(hi[e]);
    return r;
}
// async global->LDS, 16B per lane; LDS dest = wave-uniform base + lane*16
__device__ __forceinline__ void gload16(const void* g, void* lds) {
    __builtin_amdgcn_global_load_lds(
        (const __attribute__((address_space(1))) u32*)g,
        (__attribute__((address_space(3))) u32*)lds, 16, 0, 0);
}

// ---------------- kernel 1: Cayley weights -------------------------------
__global__ void k_weights(const float* __restrict__ ev, const float* __restrict__ hp,
                          const float* __restrict__ ap, float* __restrict__ br,
                          float* __restrict__ bi) {
    int k = threadIdx.x;
    float h = hp[0], alpha = ap[0];
    float t = h * (ev[k] - alpha);
    float inv = 1.0f / (t * t + 1.0f);
    float b_re = (t * t - 1.0f) * inv;
    float b_im = -2.0f * t * inv;
    float cr = b_re, ci = b_im;
    br[k] = cr; bi[k] = ci;
#pragma unroll
    for (int j = 1; j < 8; ++j) {
        float nr = cr * b_re - ci * b_im;
        float ni = cr * b_im + ci * b_re;
        cr = nr; ci = ni;
        br[j * 256 + k] = cr;
        bi[j * 256 + k] = ci;
    }
}

// ---------------- kernel 2: P_partial(bf16) = E^T @ x --------------------
// grid = chunks; block 1024 (16 waves). Tile = full 256k x full 256i.
// Window 64n reg-staged transposed+cvt to LDS (slot-XOR layout), dbuf.
// Raw s_barrier + lgkmcnt(0) only -> next window's global loads stay in
// flight across barriers (no vmcnt(0) drain).
__global__ __launch_bounds__(1024, 2) void k_gemm1(
    const float* __restrict__ E, const float* __restrict__ X,
    u16* __restrict__ Pp, int NB) {
    __shared__ alignas(16) u16 Et[2][256 * 64];   // 2 x 32 KB
    __shared__ alignas(16) u16 Xt[2][256 * 64];   // 2 x 32 KB

    int chunk = blockIdx.x;
    int nStart = chunk * NB;
    int nEnd = min(nStart + NB, NTOT);
    if (nEnd <= nStart) return;

    int t = threadIdx.x, lane = t & 63, w = t >> 6;
    int wk = w & 3, wi = w >> 2;          // 64k, 64i per wave
    int l15 = lane & 15, lhi = lane >> 4;
    int np = t & 31, cq = t >> 5;         // staging: n-pair 0..31, col-quad 0..31

    f32x4 v[8];
    f32x4 acc[4][4] = {};
    int nwin = (nEnd - nStart + 63) >> 6;

#define G1_LOAD(WIN)                                                         \
    {                                                                        \
        int nb_ = nStart + (WIN) * 64 + np * 2;                              \
        int na_ = (nb_ < nEnd) ? nb_ : nStart;                               \
        int nb2_ = (nb_ + 1 < nEnd) ? (nb_ + 1) : nStart;                    \
        float ma_ = (nb_ < nEnd) ? 1.0f : 0.0f;                              \
        float mb_ = (nb_ + 1 < nEnd) ? 1.0f : 0.0f;                          \
        _Pragma("unroll") for (int p = 0; p < 2; ++p) {                      \
            int c4 = (p * 32 + cq) * 4;                                      \
            v[p * 4 + 0] = *(const f32x4*)(E + (size_t)na_ * 256 + c4) * ma_; \
            v[p * 4 + 1] = *(const f32x4*)(E + (size_t)nb2_ * 256 + c4) * mb_;\
            v[p * 4 + 2] = *(const f32x4*)(X + (size_t)na_ * 256 + c4) * ma_; \
            v[p * 4 + 3] = *(const f32x4*)(X + (size_t)nb2_ * 256 + c4) * mb_;\
        }                                                                    \
    }

#define G1_WRITE(BUF)                                                        \
    _Pragma("unroll") for (int p = 0; p < 2; ++p) {                          \
        _Pragma("unroll") for (int e = 0; e < 4; ++e) {                      \
            int c = (p * 32 + cq) * 4 + e;                                   \
            int byte = c * 128 + (((np >> 2) ^ (c & 7)) * 16) + (np & 3) * 4; \
            *(u32*)((char*)Et[BUF] + byte) = packbf2(v[p * 4 + 0][e], v[p * 4 + 1][e]); \
            *(u32*)((char*)Xt[BUF] + byte) = packbf2(v[p * 4 + 2][e], v[p * 4 + 3][e]); \
        }                                                                    \
    }

#define G1_COMPUTE(BUF)                                                      \
    _Pragma("unroll") for (int ns = 0; ns < 2; ++ns) {                       \
        s16x8 a[4], b[4];                                                    \
        _Pragma("unroll") for (int m = 0; m < 4; ++m) {                      \
            int row = wk * 64 + m * 16 + l15;                                \
            int slot = (ns * 4 + lhi) ^ (row & 7);                           \
            a[m] = *(const s16x8*)((char*)Et[BUF] + row * 128 + slot * 16);  \
        }                                                                    \
        _Pragma("unroll") for (int c = 0; c < 4; ++c) {                      \
            int row = wi * 64 + c * 16 + l15;                                \
            int slot = (ns * 4 + lhi) ^ (row & 7);                           \
            b[c] = *(const s16x8*)((char*)Xt[BUF] + row * 128 + slot * 16);  \
        }                                                                    \
        _Pragma("unroll") for (int m = 0; m < 4; ++m)                        \
            _Pragma("unroll") for (int c = 0; c < 4; ++c)                    \
                acc[m][c] = __builtin_amdgcn_mfma_f32_16x16x32_bf16(         \
                    a[m], b[c], acc[m][c], 0, 0, 0);                         \
    }

    G1_LOAD(0);
    for (int win = 0; win < nwin; ++win) {
        asm volatile("s_waitcnt lgkmcnt(0)" ::: "memory");
        __builtin_amdgcn_s_barrier();
        G1_WRITE(win & 1);
        if (win + 1 < nwin) G1_LOAD(win + 1);
        asm volatile("s_waitcnt lgkmcnt(0)" ::: "memory");
        __builtin_amdgcn_s_barrier();
        G1_COMPUTE(win & 1);
    }
#undef G1_LOAD
#undef G1_WRITE
#undef G1_COMPUTE

    u16* dst = Pp + (size_t)chunk * 65536;
#pragma unroll
    for (int m = 0; m < 4; ++m) {
#pragma unroll
        for (int cf = 0; cf < 4; ++cf) {
            int ii = wi * 64 + cf * 16 + l15;
#pragma unroll
            for (int r = 0; r < 4; ++r) {
                int kk = wk * 64 + m * 16 + lhi * 4 + r;
                dst[kk * 256 + ii] = bfbits(acc[m][cf][r]);
            }
        }
    }
}

// ---------------- kernel 3: reduce bf16 partials -> Pb (bf16) ------------
__global__ void k_reduceP(const u16* __restrict__ Pp,
                          u16* __restrict__ Pb, int chunks) {
    int g4 = (blockIdx.x * 256 + threadIdx.x) * 4;
    float s0 = 0.f, s1 = 0.f, s2 = 0.f, s3 = 0.f;
    for (int c = 0; c < chunks; ++c) {
        s16x4 vv = *(const s16x4*)(Pp + (size_t)c * 65536 + g4);
        s0 += bf2f((u16)vv[0]); s1 += bf2f((u16)vv[1]);
        s2 += bf2f((u16)vv[2]); s3 += bf2f((u16)vv[3]);
    }
    s16x4 o;
    o[0] = (short)bfbits(s0); o[1] = (short)bfbits(s1);
    o[2] = (short)bfbits(s2); o[3] = (short)bfbits(s3);
    *(s16x4*)(Pb + g4) = o;
}

// ---------------- kernel 4: T[c] = P @ W_c^T (17 small GEMMs) ------------
__global__ __launch_bounds__(256, 4) void k_smallgemm(
    const u16* __restrict__ Pb, const float* __restrict__ c0,
    const float* __restrict__ cjr, const float* __restrict__ cji,
    float* __restrict__ T) {
    int c = blockIdx.x >> 3;
    int k0 = (blockIdx.x & 7) * 32;
    const float* W = (c == 0) ? c0 : (c <= 8 ? (cjr + (size_t)(c - 1) * 65536)
                                             : (cji + (size_t)(c - 9) * 65536));
    int t = threadIdx.x, lane = t & 63, wi = t >> 6;
    int l15 = lane & 15, lhi = lane >> 4;
    f32x4 acc[2][4] = {};
    for (int is = 0; is < 256; is += 32) {
        s16x8 a[2], b[4];
#pragma unroll
        for (int m = 0; m < 2; ++m)
            a[m] = *(const s16x8*)(Pb + (k0 + m * 16 + l15) * 256 + is + lhi * 8);
#pragma unroll
        for (int cf = 0; cf < 4; ++cf)
            b[cf] = cvt8(W + (size_t)(wi * 64 + cf * 16 + l15) * 256 + is + lhi * 8);
#pragma unroll
        for (int m = 0; m < 2; ++m)
#pragma unroll
            for (int cf = 0; cf < 4; ++cf)
                acc[m][cf] = __builtin_amdgcn_mfma_f32_16x16x32_bf16(
                    a[m], b[cf], acc[m][cf], 0, 0, 0);
    }
    float* dst = T + (size_t)c * 65536;
#pragma unroll
    for (int m = 0; m < 2; ++m) {
#pragma unroll
        for (int cf = 0; cf < 4; ++cf) {
            int oo = wi * 64 + cf * 16 + l15;
#pragma unroll
            for (int r = 0; r < 4; ++r) {
                int kk = k0 + m * 16 + lhi * 4 + r;
                dst[kk * 256 + oo] = acc[m][cf][r];
            }
        }
    }
}

// ---------------- kernel 5: combine T -> Qt bf16 (transposed) ------------
__global__ void k_combine(const float* __restrict__ T, const float* __restrict__ br,
                          const float* __restrict__ bi, u16* __restrict__ Qt) {
    int t = threadIdx.x;
    int k = blockIdx.x * 4 + (t >> 6);
    int o4 = (t & 63) * 4;
    f32x4 q = *(const f32x4*)(T + (size_t)k * 256 + o4);
#pragma unroll
    for (int j = 0; j < 8; ++j) {
        float brv = br[j * 256 + k], biv = bi[j * 256 + k];
        f32x4 tr = *(const f32x4*)(T + (size_t)(1 + j) * 65536 + k * 256 + o4);
        f32x4 ti = *(const f32x4*)(T + (size_t)(9 + j) * 65536 + k * 256 + o4);
        q += 2.0f * (brv * tr - biv * ti);
    }
#pragma unroll
    for (int e = 0; e < 4; ++e) Qt[(size_t)(o4 + e) * 256 + k] = bfbits(q[e]);
}

// ---------------- kernel 6: out = E @ Q ----------------------------------
// grid = 1024 (o-range = b>>8 of 4x64, n-chunk = b&255 of 24-25 16-row
// tiles). Qt slab (64o x 256k bf16, 32 KB) staged to LDS once via
// global_load_lds (pre-swizzled source). E tiles (16n x 256k f32, 16 KB)
// double-buffered via global_load_lds; counted vmcnt(1) at boundaries.
__global__ __launch_bounds__(256, 2) void k_gemm2(
    const float* __restrict__ E, const u16* __restrict__ Qt,
    float* __restrict__ out) {
    __shared__ alignas(16) u16 QtL[64 * 256];       // 32 KB
    __shared__ alignas(16) float Ebuf[2][4096];     // 2 x 16 KB

    int b = blockIdx.x;
    int nc = b & 255;
    int o0 = (b >> 8) * 64;
    int tile0 = nc * 24 + min(nc, 106);
    int nt = (nc < 106) ? 25 : 24;

    int t = threadIdx.x, lane = t & 63, w = t >> 6;
    int l15 = lane & 15, lhi = lane >> 4;

    // ---- stage Qt slab: 8 rounds; row o (512B) = 32 slots, slot-XOR (o&7)
#pragma unroll
    for (int r = 0; r < 8; ++r) {
        int L = r * 256 + t;
        int o = L >> 5, s = L & 31;
        gload16(Qt + (size_t)(o0 + o) * 256 + ((s ^ (o & 7)) * 8),
                (char*)QtL + (r * 256 + w * 64) * 16);
    }

#define G2_STAGE(TILE, BUF)                                                  \
    {                                                                        \
        int n0_ = (tile0 + (TILE)) * 16;                                     \
        _Pragma("unroll") for (int r = 0; r < 4; ++r) {                      \
            int L_ = r * 256 + t;                                            \
            int n_ = L_ >> 6, s_ = L_ & 63;                                  \
            gload16(E + (size_t)(n0_ + n_) * 256 + ((s_ ^ (n_ & 7)) * 4),    \
                    (char*)Ebuf[BUF] + (r * 256 + w * 64) * 16);             \
        }                                                                    \
    }

    G2_STAGE(0, 0);
    asm volatile("s_waitcnt vmcnt(0)" ::: "memory");
    __builtin_amdgcn_s_barrier();

#define G2_KSTEP(KS, EB)                                                     \
    {                                                                        \
        int orow = w * 16 + l15;                                             \
        const s16x8 a = *(const s16x8*)((const char*)QtL + orow * 512 +      \
                          ((((KS) * 4 + lhi) ^ (l15 & 7)) * 16));            \
        int q0 = (KS) * 8 + lhi * 2;                                         \
        f32x4 e0 = *(const f32x4*)((EB) + l15 * 1024 + ((q0 ^ (l15 & 7)) * 16)); \
        f32x4 e1 = *(const f32x4*)((EB) + l15 * 1024 + (((q0 + 1) ^ (l15 & 7)) * 16)); \
        s16x8 bfr;                                                           \
        _Pragma("unroll") for (int e = 0; e < 4; ++e) {                      \
            bfr[e] = (short)bfbits(e0[e]);                                   \
            bfr[4 + e] = (short)bfbits(e1[e]);                               \
        }                                                                    \
        acc = __builtin_amdgcn_mfma_f32_16x16x32_bf16(a, bfr, acc, 0, 0, 0); \
    }

    for (int i = 0; i < nt; ++i) {
        const char* Eb = (const char*)Ebuf[i & 1];
        f32x4 acc = {};
#pragma unroll
        for (int ks = 0; ks < 4; ++ks) G2_KSTEP(ks, Eb);
        if (i + 1 < nt) G2_STAGE(i + 1, (i + 1) & 1);
#pragma unroll
        for (int ks = 4; ks < 8; ++ks) G2_KSTEP(ks, Eb);
        int n = (tile0 + i) * 16 + l15;
        *(f32x4*)(out + (size_t)n * 256 + o0 + w * 16 + lhi * 4) = acc;
        if (i + 1 < nt) {
            // newest-in-queue: 1 store; next tile's 4 stage loads before it
            asm volatile("s_waitcnt vmcnt(1)" ::: "memory");
            __builtin_amdgcn_s_barrier();
        }
    }
#undef G2_STAGE
#undef G2_KSTEP
}

// ---------------- host ---------------------------------------------------
extern "C" void kernel_launch(void* const* d_in, const int* in_sizes, int n_in,
                              void* d_out, int out_size, void* d_ws, size_t ws_size,
                              hipStream_t stream) {
    const float* x   = (const float*)d_in[0];
    const float* ev  = (const float*)d_in[1];
    const float* E   = (const float*)d_in[2];
    const float* hp  = (const float*)d_in[3];
    const float* ap  = (const float*)d_in[4];
    const float* c0  = (const float*)d_in[5];
    const float* cjr = (const float*)d_in[6];
    const float* cji = (const float*)d_in[7];
    float* out = (float*)d_out;

    char* ws = (char*)d_ws;
    float* br = (float*)(ws + 0);                 // 8 KB
    float* bi = (float*)(ws + 8192);              // 8 KB
    u16*   Pb = (u16*)(ws + 16384);               // 128 KB
    u16*   Qt = (u16*)(ws + 147456);              // 128 KB
    float* T  = (float*)(ws + 278528);            // 17*256 KB
    const size_t pp_off = 4734976;
    u16*   Pp = (u16*)(ws + pp_off);              // chunks * 128 KB (bf16)

    size_t avail = (ws_size > pp_off) ? (ws_size - pp_off) : 0;
    int chunks = (int)(avail / 131072);
    if (chunks > 256) chunks = 256;
    if (chunks < 1) chunks = 1;
    int NB = (NTOT + chunks - 1) / chunks;

    k_weights<<<1, 256, 0, stream>>>(ev, hp, ap, br, bi);
    k_gemm1<<<chunks, 1024, 0, stream>>>(E, x, Pp, NB);
    k_reduceP<<<256, 256, 0, stream>>>(Pp, Pb, chunks);
    k_smallgemm<<<17 * 8, 256, 0, stream>>>(Pb, c0, cjr, cji, T);
    k_combine<<<64, 256, 0, stream>>>(T, br, bi, Qt);
    k_gemm2<<<1024, 256, 0, stream>>>(E, Qt, out);
}